// Round 4
// baseline (213.985 us; speedup 1.0000x reference)
//
#include <hip/hip_runtime.h>
#include <stdint.h>

// Problem constants (B=4, S=2048, H=1024, E=8, TOP_K=2). All I/O fp32.
#define N_TOK 8192
#define H_DIM 1024
#define N_EXP 8
#define GEMM_GRID 1280   // 5 blocks/CU x 256 CU (LDS = exactly 32KB) -> all items in ONE generation

typedef __bf16 bf16x8 __attribute__((ext_vector_type(8)));
typedef float floatx4 __attribute__((ext_vector_type(4)));

typedef __attribute__((address_space(1))) void GV;
typedef __attribute__((address_space(3))) void LV;

static __device__ __forceinline__ unsigned short f2b(float f) {
    union { float f; unsigned int i; } v; v.f = f;
    unsigned int u = v.i;
    return (unsigned short)((u + 0x7FFFu + ((u >> 16) & 1u)) >> 16);
}
static __device__ __forceinline__ float b2f(unsigned short u) {
    union { unsigned int i; float f; } v; v.i = ((unsigned int)u) << 16; return v.f;
}

// ---------------- K1: fused router (blocks 0..2047) + W repack (blocks 2048..3071) ----------------
__global__ __launch_bounds__(256) void k_front(
    const float* __restrict__ tokens,
    const float* __restrict__ router_w,
    const float* __restrict__ router_b,
    const float* __restrict__ W,
    int* __restrict__ sel, float* __restrict__ w_arr,
    unsigned short* __restrict__ tokb,
    unsigned short* __restrict__ Bp)
{
    const int t = threadIdx.x;

    if (blockIdx.x >= 2048) {
        // ---- repack W[e][h][d] fp32 -> Bp[e][h>>3][d][h&7] bf16 (no LDS) ----
        const int idx = blockIdx.x - 2048;   // 0..1023
        const int kg = idx & 127;
        const int e  = idx >> 7;
        const int d  = t * 4;                // thread owns 4 consecutive d
        const float* src = W + ((size_t)e * H_DIM + kg * 8) * H_DIM + d;
        float col[8][4];
#pragma unroll
        for (int j = 0; j < 8; ++j) {
            float4 v = *(const float4*)(src + (size_t)j * H_DIM);
            col[j][0] = v.x; col[j][1] = v.y; col[j][2] = v.z; col[j][3] = v.w;
        }
        unsigned short* dst = Bp + ((size_t)(e * 128 + kg) * H_DIM + d) * 8;
#pragma unroll
        for (int k = 0; k < 4; ++k) {
            unsigned short v[8];
#pragma unroll
            for (int j = 0; j < 8; ++j) v[j] = f2b(col[j][k]);
            *(uint4*)(dst + (size_t)k * 8) = *(uint4*)v;
        }
        return;
    }

    // ---- router: 1 wave per token, fp32, no atomics; also emit bf16 tokens ----
    const int wave = t >> 6;
    const int lane = t & 63;
    const int n = blockIdx.x * 4 + wave;

    const float* xp = tokens + (size_t)n * H_DIM + lane * 16;
    float x[16];
#pragma unroll
    for (int i = 0; i < 4; ++i) {
        float4 v = *(const float4*)(xp + i * 4);
        x[i * 4 + 0] = v.x; x[i * 4 + 1] = v.y; x[i * 4 + 2] = v.z; x[i * 4 + 3] = v.w;
    }

    {
        unsigned short xb[16];
#pragma unroll
        for (int j = 0; j < 16; ++j) xb[j] = f2b(x[j]);
        unsigned short* dp = tokb + (size_t)n * H_DIM + lane * 16;
        *(uint4*)(dp)     = *(uint4*)(xb);
        *(uint4*)(dp + 8) = *(uint4*)(xb + 8);
    }

    float acc[N_EXP];
#pragma unroll
    for (int e = 0; e < N_EXP; ++e) {
        const float* wp = router_w + e * H_DIM + lane * 16;
        float s = 0.f;
#pragma unroll
        for (int i = 0; i < 4; ++i) {
            float4 v = *(const float4*)(wp + i * 4);
            s += x[i * 4 + 0] * v.x + x[i * 4 + 1] * v.y
               + x[i * 4 + 2] * v.z + x[i * 4 + 3] * v.w;
        }
        acc[e] = s;
    }

#pragma unroll
    for (int e = 0; e < N_EXP; ++e) {
        float a = acc[e];
#pragma unroll
        for (int off = 32; off > 0; off >>= 1) a += __shfl_xor(a, off);
        acc[e] = a;
    }

    if (lane == 0) {
        float lg[N_EXP];
#pragma unroll
        for (int e = 0; e < N_EXP; ++e) lg[e] = acc[e] + router_b[e];
        int e0 = 0;
#pragma unroll
        for (int e = 1; e < N_EXP; ++e) if (lg[e] > lg[e0]) e0 = e;
        int e1 = -1;
#pragma unroll
        for (int e = 0; e < N_EXP; ++e) {
            if (e == e0) continue;
            if (e1 < 0 || lg[e] > lg[e1]) e1 = e;
        }
        // collapsed weights: w0 = p0/(p0+p1) = sigmoid(l0-l1); eps terms < fp32 ulp
        float w0 = 1.f / (1.f + __expf(lg[e1] - lg[e0]));
        float w1 = 1.f - w0;
        sel[n] = e0 | (e1 << 4);
        w_arr[n * 2] = w0;
        w_arr[n * 2 + 1] = w1;
    }
}

// ---------------- K1b: counting sort, one block per expert (deterministic) ----------------
__global__ __launch_bounds__(256) void k_scan(
    const int* __restrict__ sel, int* __restrict__ cnt, int* __restrict__ bucket)
{
    __shared__ int ssel[N_TOK + N_TOK / 32];   // padded: idx n -> n + (n>>5)
    __shared__ int sc[256];
    const int e = blockIdx.x;
    const int t = threadIdx.x;
#pragma unroll
    for (int i = 0; i < 32; ++i) {
        int n = i * 256 + t;
        ssel[n + (n >> 5)] = sel[n];
    }
    __syncthreads();
    const int base = t * 32;
    int c = 0;
#pragma unroll
    for (int i = 0; i < 32; ++i) {
        int n = base + i;
        int s = ssel[n + (n >> 5)];
        c += ((s & 15) == e) + (((s >> 4) & 15) == e);
    }
    sc[t] = c;
    __syncthreads();
    for (int off = 1; off < 256; off <<= 1) {
        int v = (t >= off) ? sc[t - off] : 0;
        __syncthreads();
        sc[t] += v;
        __syncthreads();
    }
    int pos = sc[t] - c;   // exclusive prefix
    if (t == 255) cnt[e] = sc[255];
#pragma unroll
    for (int i = 0; i < 32; ++i) {
        int n = base + i;
        int s = ssel[n + (n >> 5)];
        if ((s & 15) == e)        bucket[e * N_TOK + pos++] = 2 * n;
        if (((s >> 4) & 15) == e) bucket[e * N_TOK + pos++] = 2 * n + 1;
    }
}

// ---------------- K3: grouped GEMM, 128x128 tiles, XCD-chunked, ONE resident generation ----------------
// Work item = (row-tile, nt). T = sum ceil(cnt_e/128) in [128,135]; items = T*8 <= 1080.
// XCD x = blockIdx.x & 7 (HW round-robin, confirmed by round-3 FETCH_SIZE drop 115->29MB) owns a
// contiguous chunk of row-tiles; its 160 block-slots (grid 1280 = 5 blocks/CU, LDS exactly 32KB)
// cover up to 136 items in a SINGLE resident round -- round-3's 2nd round (6% extra work, 2x time)
// is eliminated. rows[] moved from LDS to direct bucket loads (L2-hot) to hit the 32KB boundary.
// Y row layout (per 128-col segment nt): stored index s = wc*64 + m_lane*4 + j
// holds actual col wc*64 + j*16 + m_lane.
__global__ __launch_bounds__(256, 5) void k_gemm(
    const unsigned short* __restrict__ tokb,
    const unsigned short* __restrict__ Bp,
    const int* __restrict__ cnt, const int* __restrict__ bucket,
    unsigned short* __restrict__ Y)
{
    // As: flat [row][64], XOR-swizzled: (row, part) lives at row*64 + (part^(row&7))*8
    __shared__ __align__(16) unsigned short Asm[128 * 64];     // 16 KB
    __shared__ __align__(16) unsigned short Bsm[8 * 128 * 8];  // 16 KB, chunk (kg,d) at (kg*128+d)*8

    const int t = threadIdx.x;
    const int wv = t >> 6, lane = t & 63;
    const int w_row = wv >> 1, w_col = wv & 1;
    const int m_lane = lane & 15, quad = lane >> 4;
    const int r7 = m_lane & 7;
    const int p_sw = (lane & 7) ^ ((lane >> 3) & 7);

    int cs[N_EXP];
#pragma unroll
    for (int ee = 0; ee < N_EXP; ++ee) cs[ee] = cnt[ee];
    int T = 0;
#pragma unroll
    for (int ee = 0; ee < N_EXP; ++ee) T += (cs[ee] + 127) >> 7;

    // bijective chunk split of T tiles over 8 XCDs
    const int x = blockIdx.x & 7;        // physical XCD (round-robin)
    const int sblk = blockIdx.x >> 3;    // 0..159 within XCD
    const int q = T >> 3, r = T & 7;
    const int tstart = (x < r) ? x * (q + 1) : r * (q + 1) + (x - r) * q;
    const int tcnt   = (x < r) ? (q + 1) : q;
    const int nloc   = tcnt * 8;         // <= 136 <= 160 slots: single round

    for (int l = sblk; l < nloc; l += 160) {
        const int tile = tstart + (l >> 3);
        const int nt   = l & 7;
        int base = 0, e = 0, mt = 0;
#pragma unroll
        for (int ee = 0; ee < N_EXP; ++ee) {
            int te = (cs[ee] + 127) >> 7;
            if (tile >= base && tile < base + te) { e = ee; mt = tile - base; }
            base += te;
        }
        const int cnt_local = cs[e] - mt * 128;
        const int d0 = nt * 128;
        const int* bk = bucket + e * N_TOK + mt * 128;

        // A staging: instr i, lane l covers LDS chunk c = i*256+wv*64+l
        // -> row rr = c>>3 = i*32+wv*8+(l>>3), swizzled slot l&7 holds global part p=(l&7)^(rr&7)
        const unsigned short* aptr[4];
#pragma unroll
        for (int i = 0; i < 4; ++i) {
            int rr = i * 32 + wv * 8 + (lane >> 3);
            int tok = (rr < cnt_local) ? (bk[rr] >> 1) : 0;  // inactive rows read token 0; masked at store
            aptr[i] = tokb + (size_t)tok * H_DIM + p_sw * 8;
        }
        // B staging: chunk c = i*256+t -> kg' = c>>7 = i*2+(t>>7), d = t&127
        const unsigned short* bbase = Bp
            + ((size_t)(e * 128 + (t >> 7)) * H_DIM + d0 + (t & 127)) * 8;

        floatx4 acc[4][4];
#pragma unroll
        for (int i = 0; i < 4; ++i)
#pragma unroll
            for (int j = 0; j < 4; ++j) acc[i][j] = (floatx4){0.f, 0.f, 0.f, 0.f};

        for (int kt = 0; kt < H_DIM / 64; ++kt) {
#pragma unroll
            for (int i = 0; i < 4; ++i) {
                __builtin_amdgcn_global_load_lds(
                    (GV*)(aptr[i] + kt * 64),
                    (LV*)(&Asm[i * 2048 + wv * 512]), 16, 0, 0);
                __builtin_amdgcn_global_load_lds(
                    (GV*)(bbase + (size_t)i * 16384 + (size_t)kt * 65536),
                    (LV*)(&Bsm[i * 2048 + wv * 512]), 16, 0, 0);
            }
            __syncthreads();

#pragma unroll
            for (int s = 0; s < 2; ++s) {
                bf16x8 a[4], b[4];
#pragma unroll
                for (int i = 0; i < 4; ++i) {
                    int row = w_row * 64 + i * 16 + m_lane;
                    a[i] = *(const bf16x8*)&Asm[row * 64 + ((s * 4 + quad) ^ r7) * 8];
                }
#pragma unroll
                for (int j = 0; j < 4; ++j)
                    b[j] = *(const bf16x8*)&Bsm[((s * 4 + quad) * 128 + w_col * 64 + j * 16 + m_lane) * 8];
#pragma unroll
                for (int i = 0; i < 4; ++i)
#pragma unroll
                    for (int j = 0; j < 4; ++j)
                        acc[i][j] = __builtin_amdgcn_mfma_f32_16x16x32_bf16(a[i], b[j], acc[i][j], 0, 0, 0);
            }
            __syncthreads();
        }

        // epilogue: plain bf16 stores, permuted-within-segment layout (8B per (i,reg))
#pragma unroll
        for (int i = 0; i < 4; ++i) {
            const int lr_base = w_row * 64 + i * 16 + quad * 4;
#pragma unroll
            for (int reg = 0; reg < 4; ++reg) {
                const int lr = lr_base + reg;
                if (lr < cnt_local) {
                    const int rid = bk[lr];
                    unsigned short v[4];
#pragma unroll
                    for (int j = 0; j < 4; ++j) v[j] = f2b(acc[i][j][reg]);
                    *(uint2*)(Y + (size_t)rid * H_DIM + d0 + w_col * 64 + m_lane * 4) = *(uint2*)v;
                }
            }
        }
    }
}

// ---------------- K4: combine via LDS de-permute; coalesced loads AND stores ----------------
// block = 2 tokens (4 consecutive Y rows, 8KB). Stage linear into LDS, gather the
// inverse permutation with ds_read_u16, store two float4 per thread.
__global__ __launch_bounds__(256) void k_combine(
    const unsigned short* __restrict__ Y, const float* __restrict__ w_arr,
    float* __restrict__ out)
{
    __shared__ __align__(16) unsigned short Ys[4 * H_DIM];   // rows 4b..4b+3
    const int t = threadIdx.x;
    const int b = blockIdx.x;                 // 4096 blocks, 2 tokens each
    const int wv = t >> 6, lane = t & 63;
    const unsigned short* src = Y + (size_t)b * 4 * H_DIM;
#pragma unroll
    for (int r = 0; r < 2; ++r) {
        __builtin_amdgcn_global_load_lds(
            (GV*)(src + (size_t)r * 2048 + wv * 512 + lane * 8),
            (LV*)(&Ys[r * 2048 + wv * 512]), 16, 0, 0);
    }
    __syncthreads();   // full drain is fine here (single stage)

    const int tok = t >> 7;                   // 0/1 within block
    const int n = 2 * b + tok;
    const int d0 = (t & 127) * 8;             // 8 consecutive output cols
    const int seg = d0 >> 7;
    const int dseg = d0 & 127;
    const int wc = dseg >> 6;
    const int j  = (dseg >> 4) & 3;           // constant across the 8 cols
    const int m0 = dseg & 15;                 // 0 or 8
    // stored idx within row: seg*128 + wc*64 + m*4 + j  (m = m0..m0+7)
    const int sbase = tok * 2 * H_DIM + seg * 128 + wc * 64 + j;
    const float w0 = w_arr[2 * n], w1 = w_arr[2 * n + 1];

    float o[8];
#pragma unroll
    for (int k = 0; k < 8; ++k) {
        int s = sbase + (m0 + k) * 4;
        o[k] = w0 * b2f(Ys[s]) + w1 * b2f(Ys[s + H_DIM]);
    }
    float4* op = (float4*)(out + (size_t)n * H_DIM + d0);
    op[0] = make_float4(o[0], o[1], o[2], o[3]);
    op[1] = make_float4(o[4], o[5], o[6], o[7]);
}

extern "C" void kernel_launch(void* const* d_in, const int* in_sizes, int n_in,
                              void* d_out, int out_size, void* d_ws, size_t ws_size,
                              hipStream_t stream)
{
    const float* tokens   = (const float*)d_in[0]; // fp32 [8192,1024]
    const float* router_w = (const float*)d_in[1]; // fp32 [8,1024]
    const float* router_b = (const float*)d_in[2]; // fp32 [8]
    const float* W        = (const float*)d_in[3]; // fp32 [8,1024,1024]
    float* out = (float*)d_out;                    // fp32 [8192,1024]

    char* ws = (char*)d_ws;
    int*   cnt    = (int*)(ws);                        // 32 B
    int*   sel    = (int*)(ws + 1024);                 // 32 KB
    float* w_arr  = (float*)(ws + 34816);              // 64 KB
    int*   bucket = (int*)(ws + 100352);               // 256 KB
    unsigned short* tokb = (unsigned short*)(ws + 362496);    // 16 MB bf16 tokens  [ends 17139712]
    unsigned short* Bp   = (unsigned short*)(ws + 17139712);  // 16 MB packed bf16 W [ends 33916928]
    unsigned short* Y    = (unsigned short*)(ws + 33916928);  // 32 MB bf16 per-slot outputs (AFTER Bp!)

    k_front  <<<2048 + 1024, 256, 0, stream>>>(tokens, router_w, router_b, W,
                                               sel, w_arr, tokb, Bp);
    k_scan   <<<N_EXP, 256, 0, stream>>>(sel, cnt, bucket);
    k_gemm   <<<GEMM_GRID, 256, 0, stream>>>(tokb, Bp, cnt, bucket, Y);
    k_combine<<<N_TOK * (H_DIM / 8) / 256, 256, 0, stream>>>(Y, w_arr, out);
}

// Round 5
// 201.802 us; speedup vs baseline: 1.0604x; 1.0604x over previous
//
#include <hip/hip_runtime.h>
#include <stdint.h>

// Problem constants (B=4, S=2048, H=1024, E=8, TOP_K=2). All I/O fp32.
#define N_TOK 8192
#define H_DIM 1024
#define N_EXP 8
#define GEMM_GRID 1024   // 4 blocks/CU (register-limited: 64 VGPR + 64 acc = 128/wave) x 256 CU

typedef __bf16 bf16x8 __attribute__((ext_vector_type(8)));
typedef float floatx4 __attribute__((ext_vector_type(4)));

typedef __attribute__((address_space(1))) void GV;
typedef __attribute__((address_space(3))) void LV;

static __device__ __forceinline__ unsigned short f2b(float f) {
    union { float f; unsigned int i; } v; v.f = f;
    unsigned int u = v.i;
    return (unsigned short)((u + 0x7FFFu + ((u >> 16) & 1u)) >> 16);
}
static __device__ __forceinline__ float b2f(unsigned short u) {
    union { unsigned int i; float f; } v; v.i = ((unsigned int)u) << 16; return v.f;
}

// ---------------- K1: fused router (blocks 0..2047) + W repack (blocks 2048..3071) ----------------
__global__ __launch_bounds__(256) void k_front(
    const float* __restrict__ tokens,
    const float* __restrict__ router_w,
    const float* __restrict__ router_b,
    const float* __restrict__ W,
    int* __restrict__ sel, float* __restrict__ w_arr,
    unsigned short* __restrict__ tokb,
    unsigned short* __restrict__ Bp)
{
    const int t = threadIdx.x;

    if (blockIdx.x >= 2048) {
        // ---- repack W[e][h][d] fp32 -> Bp[e][h>>3][d][h&7] bf16 (no LDS) ----
        const int idx = blockIdx.x - 2048;   // 0..1023
        const int kg = idx & 127;
        const int e  = idx >> 7;
        const int d  = t * 4;                // thread owns 4 consecutive d
        const float* src = W + ((size_t)e * H_DIM + kg * 8) * H_DIM + d;
        float col[8][4];
#pragma unroll
        for (int j = 0; j < 8; ++j) {
            float4 v = *(const float4*)(src + (size_t)j * H_DIM);
            col[j][0] = v.x; col[j][1] = v.y; col[j][2] = v.z; col[j][3] = v.w;
        }
        unsigned short* dst = Bp + ((size_t)(e * 128 + kg) * H_DIM + d) * 8;
#pragma unroll
        for (int k = 0; k < 4; ++k) {
            unsigned short v[8];
#pragma unroll
            for (int j = 0; j < 8; ++j) v[j] = f2b(col[j][k]);
            *(uint4*)(dst + (size_t)k * 8) = *(uint4*)v;
        }
        return;
    }

    // ---- router: 1 wave per token, fp32, no atomics; also emit bf16 tokens ----
    const int wave = t >> 6;
    const int lane = t & 63;
    const int n = blockIdx.x * 4 + wave;

    const float* xp = tokens + (size_t)n * H_DIM + lane * 16;
    float x[16];
#pragma unroll
    for (int i = 0; i < 4; ++i) {
        float4 v = *(const float4*)(xp + i * 4);
        x[i * 4 + 0] = v.x; x[i * 4 + 1] = v.y; x[i * 4 + 2] = v.z; x[i * 4 + 3] = v.w;
    }

    {
        unsigned short xb[16];
#pragma unroll
        for (int j = 0; j < 16; ++j) xb[j] = f2b(x[j]);
        unsigned short* dp = tokb + (size_t)n * H_DIM + lane * 16;
        *(uint4*)(dp)     = *(uint4*)(xb);
        *(uint4*)(dp + 8) = *(uint4*)(xb + 8);
    }

    float acc[N_EXP];
#pragma unroll
    for (int e = 0; e < N_EXP; ++e) {
        const float* wp = router_w + e * H_DIM + lane * 16;
        float s = 0.f;
#pragma unroll
        for (int i = 0; i < 4; ++i) {
            float4 v = *(const float4*)(wp + i * 4);
            s += x[i * 4 + 0] * v.x + x[i * 4 + 1] * v.y
               + x[i * 4 + 2] * v.z + x[i * 4 + 3] * v.w;
        }
        acc[e] = s;
    }

#pragma unroll
    for (int e = 0; e < N_EXP; ++e) {
        float a = acc[e];
#pragma unroll
        for (int off = 32; off > 0; off >>= 1) a += __shfl_xor(a, off);
        acc[e] = a;
    }

    if (lane == 0) {
        float lg[N_EXP];
#pragma unroll
        for (int e = 0; e < N_EXP; ++e) lg[e] = acc[e] + router_b[e];
        int e0 = 0;
#pragma unroll
        for (int e = 1; e < N_EXP; ++e) if (lg[e] > lg[e0]) e0 = e;
        int e1 = -1;
#pragma unroll
        for (int e = 0; e < N_EXP; ++e) {
            if (e == e0) continue;
            if (e1 < 0 || lg[e] > lg[e1]) e1 = e;
        }
        // collapsed weights: w0 = p0/(p0+p1) = sigmoid(l0-l1); eps terms < fp32 ulp
        float w0 = 1.f / (1.f + __expf(lg[e1] - lg[e0]));
        float w1 = 1.f - w0;
        sel[n] = e0 | (e1 << 4);
        w_arr[n * 2] = w0;
        w_arr[n * 2 + 1] = w1;
    }
}

// ---------------- K1b: counting sort, one block per expert (deterministic) ----------------
__global__ __launch_bounds__(256) void k_scan(
    const int* __restrict__ sel, int* __restrict__ cnt, int* __restrict__ bucket)
{
    __shared__ int ssel[N_TOK + N_TOK / 32];   // padded: idx n -> n + (n>>5)
    __shared__ int sc[256];
    const int e = blockIdx.x;
    const int t = threadIdx.x;
#pragma unroll
    for (int i = 0; i < 32; ++i) {
        int n = i * 256 + t;
        ssel[n + (n >> 5)] = sel[n];
    }
    __syncthreads();
    const int base = t * 32;
    int c = 0;
#pragma unroll
    for (int i = 0; i < 32; ++i) {
        int n = base + i;
        int s = ssel[n + (n >> 5)];
        c += ((s & 15) == e) + (((s >> 4) & 15) == e);
    }
    sc[t] = c;
    __syncthreads();
    for (int off = 1; off < 256; off <<= 1) {
        int v = (t >= off) ? sc[t - off] : 0;
        __syncthreads();
        sc[t] += v;
        __syncthreads();
    }
    int pos = sc[t] - c;   // exclusive prefix
    if (t == 255) cnt[e] = sc[255];
#pragma unroll
    for (int i = 0; i < 32; ++i) {
        int n = base + i;
        int s = ssel[n + (n >> 5)];
        if ((s & 15) == e)        bucket[e * N_TOK + pos++] = 2 * n;
        if (((s >> 4) & 15) == e) bucket[e * N_TOK + pos++] = 2 * n + 1;
    }
}

// ---------------- K3: grouped GEMM, 128x128 tiles, XCD-chunked, BK=32 double-buffered ----------------
// Round-3 proven: XCD chunking (FETCH 115->29MB), grid 1024, (256,4), rows[] in LDS.
// New: T3-minimum 2-phase pipeline at BK=32 so the double buffer fits the SAME 33,280B LDS
// (A 2x8KB + B 2x8KB + rows 512B) -> occupancy stays 4 blocks/CU (register-limited at
// 64 VGPR + 64 acc = 128/wave = 4 waves/SIMD; round-4's (256,5) spilled 16MB to scratch).
// Per kt: issue next tile's 4 global_load_lds, compute 16 MFMA/wave from current buffer,
// one __syncthreads() (drain covers loads issued one full compute-phase earlier).
// A LDS layout [2][128 rows][32], 16B slot s holds part p with s = p ^ (r&3) ^ ((r>>2)&3)
// (8-lane read groups cover all 32 banks -> uniform, like round 3's 8-slot XOR).
// Y row layout (per 128-col segment nt): stored index s = wc*64 + m_lane*4 + j
// holds actual col wc*64 + j*16 + m_lane.
__global__ __launch_bounds__(256, 4) void k_gemm(
    const unsigned short* __restrict__ tokb,
    const unsigned short* __restrict__ Bp,
    const int* __restrict__ cnt, const int* __restrict__ bucket,
    unsigned short* __restrict__ Y)
{
    __shared__ __align__(16) unsigned short Asm[2][128 * 32];    // 2 x 8 KB
    __shared__ __align__(16) unsigned short Bsm[2][4 * 128 * 8]; // 2 x 8 KB, (kg,d) at (kg*128+d)*8
    __shared__ int rows[128];

    const int t = threadIdx.x;
    const int wv = t >> 6, lane = t & 63;
    const int w_row = wv >> 1, w_col = wv & 1;
    const int m_lane = lane & 15, quad = lane >> 4;
    // A read slot (16B units within a 32-elem row): part quad lives at quad ^ f(r)
    const int aslot = quad ^ (m_lane & 3) ^ ((m_lane >> 2) & 3);
    // A staging: thread t covers slot t&3 of row (t>>2) (+64 for 2nd instr); source part:
    const int p_sw = (t & 3) ^ ((t >> 2) & 3) ^ ((t >> 4) & 3);

    int cs[N_EXP];
#pragma unroll
    for (int ee = 0; ee < N_EXP; ++ee) cs[ee] = cnt[ee];
    int T = 0;
#pragma unroll
    for (int ee = 0; ee < N_EXP; ++ee) T += (cs[ee] + 127) >> 7;

    // bijective chunk split of T tiles over 8 XCDs (XCD = blockIdx.x & 7, HW round-robin)
    const int x = blockIdx.x & 7;
    const int sblk = blockIdx.x >> 3;    // 0..127 within XCD
    const int q = T >> 3, r = T & 7;
    const int tstart = (x < r) ? x * (q + 1) : r * (q + 1) + (x - r) * q;
    const int tcnt   = (x < r) ? (q + 1) : q;
    const int nloc   = tcnt * 8;

    for (int l = sblk; l < nloc; l += 128) {
        const int tile = tstart + (l >> 3);
        const int nt   = l & 7;
        int base = 0, e = 0, mt = 0;
#pragma unroll
        for (int ee = 0; ee < N_EXP; ++ee) {
            int te = (cs[ee] + 127) >> 7;
            if (tile >= base && tile < base + te) { e = ee; mt = tile - base; }
            base += te;
        }
        const int cnt_local = cs[e] - mt * 128;
        const int d0 = nt * 128;

        __syncthreads();   // previous item fully done with rows/LDS
        if (t < 128)
            rows[t] = (t < cnt_local) ? bucket[e * N_TOK + mt * 128 + t] : -1;
        __syncthreads();

        // A staging sources: instr i2 covers row i2*64 + (t>>2), slot t&3 = part p_sw
        const int r0 = t >> 2;
        const int rid0 = rows[r0], rid1 = rows[64 + r0];
        const unsigned short* aptr0 = tokb + (size_t)((rid0 >= 0) ? (rid0 >> 1) : 0) * H_DIM + p_sw * 8;
        const unsigned short* aptr1 = tokb + (size_t)((rid1 >= 0) ? (rid1 >> 1) : 0) * H_DIM + p_sw * 8;
        // B staging: instr i2 covers kg = i2*2 + (t>>7), d = t&127; per-kt advance = 4 rows of Bp
        const int kgt = t >> 7;
        const unsigned short* bb0 = Bp + ((size_t)(e * 128 + kgt)     * H_DIM + d0 + (t & 127)) * 8;
        const unsigned short* bb1 = Bp + ((size_t)(e * 128 + 2 + kgt) * H_DIM + d0 + (t & 127)) * 8;

        floatx4 acc[4][4];
#pragma unroll
        for (int i = 0; i < 4; ++i)
#pragma unroll
            for (int j = 0; j < 4; ++j) acc[i][j] = (floatx4){0.f, 0.f, 0.f, 0.f};

        // prologue: stage kt=0 into buffer 0
        __builtin_amdgcn_global_load_lds((GV*)aptr0, (LV*)(&Asm[0][wv * 512]), 16, 0, 0);
        __builtin_amdgcn_global_load_lds((GV*)aptr1, (LV*)(&Asm[0][2048 + wv * 512]), 16, 0, 0);
        __builtin_amdgcn_global_load_lds((GV*)bb0,   (LV*)(&Bsm[0][wv * 512]), 16, 0, 0);
        __builtin_amdgcn_global_load_lds((GV*)bb1,   (LV*)(&Bsm[0][2048 + wv * 512]), 16, 0, 0);
        __syncthreads();

        for (int kt = 0; kt < H_DIM / 32; ++kt) {
            const int cb = kt & 1;
            if (kt < H_DIM / 32 - 1) {
                const int kn = kt + 1;
                __builtin_amdgcn_global_load_lds(
                    (GV*)(aptr0 + kn * 32), (LV*)(&Asm[cb ^ 1][wv * 512]), 16, 0, 0);
                __builtin_amdgcn_global_load_lds(
                    (GV*)(aptr1 + kn * 32), (LV*)(&Asm[cb ^ 1][2048 + wv * 512]), 16, 0, 0);
                __builtin_amdgcn_global_load_lds(
                    (GV*)(bb0 + (size_t)kn * 32768), (LV*)(&Bsm[cb ^ 1][wv * 512]), 16, 0, 0);
                __builtin_amdgcn_global_load_lds(
                    (GV*)(bb1 + (size_t)kn * 32768), (LV*)(&Bsm[cb ^ 1][2048 + wv * 512]), 16, 0, 0);
            }

            bf16x8 a[4], b[4];
#pragma unroll
            for (int i = 0; i < 4; ++i) {
                int row = w_row * 64 + i * 16 + m_lane;
                a[i] = *(const bf16x8*)&Asm[cb][row * 32 + aslot * 8];
            }
#pragma unroll
            for (int j = 0; j < 4; ++j)
                b[j] = *(const bf16x8*)&Bsm[cb][(quad * 128 + w_col * 64 + j * 16 + m_lane) * 8];
#pragma unroll
            for (int i = 0; i < 4; ++i)
#pragma unroll
                for (int j = 0; j < 4; ++j)
                    acc[i][j] = __builtin_amdgcn_mfma_f32_16x16x32_bf16(a[i], b[j], acc[i][j], 0, 0, 0);

            __syncthreads();   // drains the prefetch (issued one compute-phase ago) + WAR protect
        }

        // epilogue: plain bf16 stores, permuted-within-segment layout (8B per (i,reg))
#pragma unroll
        for (int i = 0; i < 4; ++i) {
            const int lr_base = w_row * 64 + i * 16 + quad * 4;
#pragma unroll
            for (int reg = 0; reg < 4; ++reg) {
                const int lr = lr_base + reg;
                const int rid = rows[lr];
                if (rid >= 0) {
                    unsigned short v[4];
#pragma unroll
                    for (int j = 0; j < 4; ++j) v[j] = f2b(acc[i][j][reg]);
                    *(uint2*)(Y + (size_t)rid * H_DIM + d0 + w_col * 64 + m_lane * 4) = *(uint2*)v;
                }
            }
        }
    }
}

// ---------------- K4: combine via LDS de-permute; coalesced loads AND stores ----------------
// block = 2 tokens (4 consecutive Y rows, 8KB). Stage linear into LDS, gather the
// inverse permutation with ds_read_u16, store two float4 per thread.
__global__ __launch_bounds__(256) void k_combine(
    const unsigned short* __restrict__ Y, const float* __restrict__ w_arr,
    float* __restrict__ out)
{
    __shared__ __align__(16) unsigned short Ys[4 * H_DIM];   // rows 4b..4b+3
    const int t = threadIdx.x;
    const int b = blockIdx.x;                 // 4096 blocks, 2 tokens each
    const int wv = t >> 6, lane = t & 63;
    const unsigned short* src = Y + (size_t)b * 4 * H_DIM;
#pragma unroll
    for (int r = 0; r < 2; ++r) {
        __builtin_amdgcn_global_load_lds(
            (GV*)(src + (size_t)r * 2048 + wv * 512 + lane * 8),
            (LV*)(&Ys[r * 2048 + wv * 512]), 16, 0, 0);
    }
    __syncthreads();   // full drain is fine here (single stage)

    const int tok = t >> 7;                   // 0/1 within block
    const int n = 2 * b + tok;
    const int d0 = (t & 127) * 8;             // 8 consecutive output cols
    const int seg = d0 >> 7;
    const int dseg = d0 & 127;
    const int wc = dseg >> 6;
    const int j  = (dseg >> 4) & 3;           // constant across the 8 cols
    const int m0 = dseg & 15;                 // 0 or 8
    // stored idx within row: seg*128 + wc*64 + m*4 + j  (m = m0..m0+7)
    const int sbase = tok * 2 * H_DIM + seg * 128 + wc * 64 + j;
    const float w0 = w_arr[2 * n], w1 = w_arr[2 * n + 1];

    float o[8];
#pragma unroll
    for (int k = 0; k < 8; ++k) {
        int s = sbase + (m0 + k) * 4;
        o[k] = w0 * b2f(Ys[s]) + w1 * b2f(Ys[s + H_DIM]);
    }
    float4* op = (float4*)(out + (size_t)n * H_DIM + d0);
    op[0] = make_float4(o[0], o[1], o[2], o[3]);
    op[1] = make_float4(o[4], o[5], o[6], o[7]);
}

extern "C" void kernel_launch(void* const* d_in, const int* in_sizes, int n_in,
                              void* d_out, int out_size, void* d_ws, size_t ws_size,
                              hipStream_t stream)
{
    const float* tokens   = (const float*)d_in[0]; // fp32 [8192,1024]
    const float* router_w = (const float*)d_in[1]; // fp32 [8,1024]
    const float* router_b = (const float*)d_in[2]; // fp32 [8]
    const float* W        = (const float*)d_in[3]; // fp32 [8,1024,1024]
    float* out = (float*)d_out;                    // fp32 [8192,1024]

    char* ws = (char*)d_ws;
    int*   cnt    = (int*)(ws);                        // 32 B
    int*   sel    = (int*)(ws + 1024);                 // 32 KB
    float* w_arr  = (float*)(ws + 34816);              // 64 KB
    int*   bucket = (int*)(ws + 100352);               // 256 KB
    unsigned short* tokb = (unsigned short*)(ws + 362496);    // 16 MB bf16 tokens  [ends 17139712]
    unsigned short* Bp   = (unsigned short*)(ws + 17139712);  // 16 MB packed bf16 W [ends 33916928]
    unsigned short* Y    = (unsigned short*)(ws + 33916928);  // 32 MB bf16 per-slot outputs (AFTER Bp!)

    k_front  <<<2048 + 1024, 256, 0, stream>>>(tokens, router_w, router_b, W,
                                               sel, w_arr, tokb, Bp);
    k_scan   <<<N_EXP, 256, 0, stream>>>(sel, cnt, bucket);
    k_gemm   <<<GEMM_GRID, 256, 0, stream>>>(tokb, Bp, cnt, bucket, Y);
    k_combine<<<N_TOK * (H_DIM / 8) / 256, 256, 0, stream>>>(Y, w_arr, out);
}

// Round 6
// 198.454 us; speedup vs baseline: 1.0783x; 1.0169x over previous
//
#include <hip/hip_runtime.h>
#include <stdint.h>

// Problem constants (B=4, S=2048, H=1024, E=8, TOP_K=2). All I/O fp32.
#define N_TOK 8192
#define H_DIM 1024
#define N_EXP 8
#define GEMM_GRID 1024   // 4 blocks/CU (register-limited: ~60 VGPR + 64 acc = 124/wave) x 256 CU

typedef __bf16 bf16x8 __attribute__((ext_vector_type(8)));
typedef float floatx4 __attribute__((ext_vector_type(4)));

typedef __attribute__((address_space(1))) void GV;
typedef __attribute__((address_space(3))) void LV;

static __device__ __forceinline__ unsigned short f2b(float f) {
    union { float f; unsigned int i; } v; v.f = f;
    unsigned int u = v.i;
    return (unsigned short)((u + 0x7FFFu + ((u >> 16) & 1u)) >> 16);
}
static __device__ __forceinline__ float b2f(unsigned short u) {
    union { unsigned int i; float f; } v; v.i = ((unsigned int)u) << 16; return v.f;
}

// ---------------- K1: fused router (blocks 0..2047) + W repack (blocks 2048..3071) ----------------
__global__ __launch_bounds__(256) void k_front(
    const float* __restrict__ tokens,
    const float* __restrict__ router_w,
    const float* __restrict__ router_b,
    const float* __restrict__ W,
    int* __restrict__ sel, float* __restrict__ w_arr,
    unsigned short* __restrict__ tokb,
    unsigned short* __restrict__ Bp)
{
    const int t = threadIdx.x;

    if (blockIdx.x >= 2048) {
        // ---- repack W[e][h][d] fp32 -> Bp[e][h>>3][d][h&7] bf16 (no LDS) ----
        const int idx = blockIdx.x - 2048;   // 0..1023
        const int kg = idx & 127;
        const int e  = idx >> 7;
        const int d  = t * 4;                // thread owns 4 consecutive d
        const float* src = W + ((size_t)e * H_DIM + kg * 8) * H_DIM + d;
        float col[8][4];
#pragma unroll
        for (int j = 0; j < 8; ++j) {
            float4 v = *(const float4*)(src + (size_t)j * H_DIM);
            col[j][0] = v.x; col[j][1] = v.y; col[j][2] = v.z; col[j][3] = v.w;
        }
        unsigned short* dst = Bp + ((size_t)(e * 128 + kg) * H_DIM + d) * 8;
#pragma unroll
        for (int k = 0; k < 4; ++k) {
            unsigned short v[8];
#pragma unroll
            for (int j = 0; j < 8; ++j) v[j] = f2b(col[j][k]);
            *(uint4*)(dst + (size_t)k * 8) = *(uint4*)v;
        }
        return;
    }

    // ---- router: 1 wave per token, fp32, no atomics; also emit bf16 tokens ----
    const int wave = t >> 6;
    const int lane = t & 63;
    const int n = blockIdx.x * 4 + wave;

    const float* xp = tokens + (size_t)n * H_DIM + lane * 16;
    float x[16];
#pragma unroll
    for (int i = 0; i < 4; ++i) {
        float4 v = *(const float4*)(xp + i * 4);
        x[i * 4 + 0] = v.x; x[i * 4 + 1] = v.y; x[i * 4 + 2] = v.z; x[i * 4 + 3] = v.w;
    }

    {
        unsigned short xb[16];
#pragma unroll
        for (int j = 0; j < 16; ++j) xb[j] = f2b(x[j]);
        unsigned short* dp = tokb + (size_t)n * H_DIM + lane * 16;
        *(uint4*)(dp)     = *(uint4*)(xb);
        *(uint4*)(dp + 8) = *(uint4*)(xb + 8);
    }

    float acc[N_EXP];
#pragma unroll
    for (int e = 0; e < N_EXP; ++e) {
        const float* wp = router_w + e * H_DIM + lane * 16;
        float s = 0.f;
#pragma unroll
        for (int i = 0; i < 4; ++i) {
            float4 v = *(const float4*)(wp + i * 4);
            s += x[i * 4 + 0] * v.x + x[i * 4 + 1] * v.y
               + x[i * 4 + 2] * v.z + x[i * 4 + 3] * v.w;
        }
        acc[e] = s;
    }

#pragma unroll
    for (int e = 0; e < N_EXP; ++e) {
        float a = acc[e];
#pragma unroll
        for (int off = 32; off > 0; off >>= 1) a += __shfl_xor(a, off);
        acc[e] = a;
    }

    if (lane == 0) {
        float lg[N_EXP];
#pragma unroll
        for (int e = 0; e < N_EXP; ++e) lg[e] = acc[e] + router_b[e];
        int e0 = 0;
#pragma unroll
        for (int e = 1; e < N_EXP; ++e) if (lg[e] > lg[e0]) e0 = e;
        int e1 = -1;
#pragma unroll
        for (int e = 0; e < N_EXP; ++e) {
            if (e == e0) continue;
            if (e1 < 0 || lg[e] > lg[e1]) e1 = e;
        }
        // collapsed weights: w0 = p0/(p0+p1) = sigmoid(l0-l1); eps terms < fp32 ulp
        float w0 = 1.f / (1.f + __expf(lg[e1] - lg[e0]));
        float w1 = 1.f - w0;
        sel[n] = e0 | (e1 << 4);
        w_arr[n * 2] = w0;
        w_arr[n * 2 + 1] = w1;
    }
}

// ---------------- K1b: counting sort, one block per expert (deterministic) ----------------
__global__ __launch_bounds__(256) void k_scan(
    const int* __restrict__ sel, int* __restrict__ cnt, int* __restrict__ bucket)
{
    __shared__ int ssel[N_TOK + N_TOK / 32];   // padded: idx n -> n + (n>>5)
    __shared__ int sc[256];
    const int e = blockIdx.x;
    const int t = threadIdx.x;
#pragma unroll
    for (int i = 0; i < 32; ++i) {
        int n = i * 256 + t;
        ssel[n + (n >> 5)] = sel[n];
    }
    __syncthreads();
    const int base = t * 32;
    int c = 0;
#pragma unroll
    for (int i = 0; i < 32; ++i) {
        int n = base + i;
        int s = ssel[n + (n >> 5)];
        c += ((s & 15) == e) + (((s >> 4) & 15) == e);
    }
    sc[t] = c;
    __syncthreads();
    for (int off = 1; off < 256; off <<= 1) {
        int v = (t >= off) ? sc[t - off] : 0;
        __syncthreads();
        sc[t] += v;
        __syncthreads();
    }
    int pos = sc[t] - c;   // exclusive prefix
    if (t == 255) cnt[e] = sc[255];
#pragma unroll
    for (int i = 0; i < 32; ++i) {
        int n = base + i;
        int s = ssel[n + (n >> 5)];
        if ((s & 15) == e)        bucket[e * N_TOK + pos++] = 2 * n;
        if (((s >> 4) & 15) == e) bucket[e * N_TOK + pos++] = 2 * n + 1;
    }
}

// ---------------- K3: grouped GEMM, 128x128 tiles, XCD-chunked, counted-vmcnt pipeline ----------------
// Round-3 proven: XCD chunking (FETCH 115->29MB), grid 1024, (256,4), rows[] in LDS.
// Round-5 lesson: __syncthreads() drains vmcnt(0) -> prefetch killed (m99/m100 failure mode).
// This round (T4, m218): raw s_barrier + counted s_waitcnt vmcnt(4) so the 4 prefetch loads for
// kt+1 stay IN FLIGHT across the barrier; they complete under a full iteration (~700+ cyc >= L2
// latency). Two barriers/kt: (A) after vmcnt wait = all waves' buf[cb] writes landed;
// (B) after compute = all reads of buf[cb] done before next iteration's DMA overwrites it.
// T5 setprio(1) wraps the MFMA cluster (phase role-split now exists).
// A LDS layout [2][128 rows][32], 16B slot s holds part p with s = p ^ (r&3) ^ ((r>>2)&3)
// (each 8-lane read phase covers all 32 banks). B chunk (kg,d) at (kg*128+d)*8.
// Y row layout (per 128-col segment nt): stored index s = wc*64 + m_lane*4 + j
// holds actual col wc*64 + j*16 + m_lane.
__global__ __launch_bounds__(256, 4) void k_gemm(
    const unsigned short* __restrict__ tokb,
    const unsigned short* __restrict__ Bp,
    const int* __restrict__ cnt, const int* __restrict__ bucket,
    unsigned short* __restrict__ Y)
{
    __shared__ __align__(16) unsigned short Asm[2][128 * 32];    // 2 x 8 KB
    __shared__ __align__(16) unsigned short Bsm[2][4 * 128 * 8]; // 2 x 8 KB, (kg,d) at (kg*128+d)*8
    __shared__ int rows[128];

    const int t = threadIdx.x;
    const int wv = t >> 6, lane = t & 63;
    const int w_row = wv >> 1, w_col = wv & 1;
    const int m_lane = lane & 15, quad = lane >> 4;
    // A read slot (16B units within a 32-elem row): part quad lives at quad ^ f(r)
    const int aslot = quad ^ (m_lane & 3) ^ ((m_lane >> 2) & 3);
    // A staging: thread t covers slot t&3 of row (t>>2) (+64 for 2nd instr); source part:
    const int p_sw = (t & 3) ^ ((t >> 2) & 3) ^ ((t >> 4) & 3);

    int cs[N_EXP];
#pragma unroll
    for (int ee = 0; ee < N_EXP; ++ee) cs[ee] = cnt[ee];
    int T = 0;
#pragma unroll
    for (int ee = 0; ee < N_EXP; ++ee) T += (cs[ee] + 127) >> 7;

    // bijective chunk split of T tiles over 8 XCDs (XCD = blockIdx.x & 7, HW round-robin)
    const int x = blockIdx.x & 7;
    const int sblk = blockIdx.x >> 3;    // 0..127 within XCD
    const int q = T >> 3, r = T & 7;
    const int tstart = (x < r) ? x * (q + 1) : r * (q + 1) + (x - r) * q;
    const int tcnt   = (x < r) ? (q + 1) : q;
    const int nloc   = tcnt * 8;

    for (int l = sblk; l < nloc; l += 128) {
        const int tile = tstart + (l >> 3);
        const int nt   = l & 7;
        int base = 0, e = 0, mt = 0;
#pragma unroll
        for (int ee = 0; ee < N_EXP; ++ee) {
            int te = (cs[ee] + 127) >> 7;
            if (tile >= base && tile < base + te) { e = ee; mt = tile - base; }
            base += te;
        }
        const int cnt_local = cs[e] - mt * 128;
        const int d0 = nt * 128;

        __syncthreads();   // previous item fully done with rows/LDS
        if (t < 128)
            rows[t] = (t < cnt_local) ? bucket[e * N_TOK + mt * 128 + t] : -1;
        __syncthreads();

        // A staging sources: instr i2 covers row i2*64 + (t>>2), slot t&3 = part p_sw
        const int r0 = t >> 2;
        const int rid0 = rows[r0], rid1 = rows[64 + r0];
        const unsigned short* aptr0 = tokb + (size_t)((rid0 >= 0) ? (rid0 >> 1) : 0) * H_DIM + p_sw * 8;
        const unsigned short* aptr1 = tokb + (size_t)((rid1 >= 0) ? (rid1 >> 1) : 0) * H_DIM + p_sw * 8;
        // B staging: instr i2 covers kg = i2*2 + (t>>7), d = t&127; per-kt advance = 4 rows of Bp
        const int kgt = t >> 7;
        const unsigned short* bb0 = Bp + ((size_t)(e * 128 + kgt)     * H_DIM + d0 + (t & 127)) * 8;
        const unsigned short* bb1 = Bp + ((size_t)(e * 128 + 2 + kgt) * H_DIM + d0 + (t & 127)) * 8;

        floatx4 acc[4][4];
#pragma unroll
        for (int i = 0; i < 4; ++i)
#pragma unroll
            for (int j = 0; j < 4; ++j) acc[i][j] = (floatx4){0.f, 0.f, 0.f, 0.f};

        // prologue: stage kt=0 into buffer 0 (4 loads in flight)
        __builtin_amdgcn_global_load_lds((GV*)aptr0, (LV*)(&Asm[0][wv * 512]), 16, 0, 0);
        __builtin_amdgcn_global_load_lds((GV*)aptr1, (LV*)(&Asm[0][2048 + wv * 512]), 16, 0, 0);
        __builtin_amdgcn_global_load_lds((GV*)bb0,   (LV*)(&Bsm[0][wv * 512]), 16, 0, 0);
        __builtin_amdgcn_global_load_lds((GV*)bb1,   (LV*)(&Bsm[0][2048 + wv * 512]), 16, 0, 0);

        for (int kt = 0; kt < H_DIM / 32; ++kt) {
            const int cb = kt & 1;
            if (kt < H_DIM / 32 - 1) {
                const int kn = kt + 1;
                // issue prefetch for kt+1 into buf[cb^1]; stays in flight across the barrier
                __builtin_amdgcn_global_load_lds(
                    (GV*)(aptr0 + kn * 32), (LV*)(&Asm[cb ^ 1][wv * 512]), 16, 0, 0);
                __builtin_amdgcn_global_load_lds(
                    (GV*)(aptr1 + kn * 32), (LV*)(&Asm[cb ^ 1][2048 + wv * 512]), 16, 0, 0);
                __builtin_amdgcn_global_load_lds(
                    (GV*)(bb0 + (size_t)kn * 32768), (LV*)(&Bsm[cb ^ 1][wv * 512]), 16, 0, 0);
                __builtin_amdgcn_global_load_lds(
                    (GV*)(bb1 + (size_t)kn * 32768), (LV*)(&Bsm[cb ^ 1][2048 + wv * 512]), 16, 0, 0);
                asm volatile("s_waitcnt vmcnt(4)" ::: "memory");   // kt's 4 loads done; kt+1's 4 in flight
            } else {
                asm volatile("s_waitcnt vmcnt(0)" ::: "memory");
            }
            __builtin_amdgcn_s_barrier();       // (A) all waves' buf[cb] writes landed
            asm volatile("" ::: "memory");

            bf16x8 a[4], b[4];
#pragma unroll
            for (int i = 0; i < 4; ++i) {
                int row = w_row * 64 + i * 16 + m_lane;
                a[i] = *(const bf16x8*)&Asm[cb][row * 32 + aslot * 8];
            }
#pragma unroll
            for (int j = 0; j < 4; ++j)
                b[j] = *(const bf16x8*)&Bsm[cb][(quad * 128 + w_col * 64 + j * 16 + m_lane) * 8];
            __builtin_amdgcn_s_setprio(1);
#pragma unroll
            for (int i = 0; i < 4; ++i)
#pragma unroll
                for (int j = 0; j < 4; ++j)
                    acc[i][j] = __builtin_amdgcn_mfma_f32_16x16x32_bf16(a[i], b[j], acc[i][j], 0, 0, 0);
            __builtin_amdgcn_s_setprio(0);

            asm volatile("" ::: "memory");
            __builtin_amdgcn_s_barrier();       // (B) all reads of buf[cb] done before it is overwritten
        }

        // epilogue: plain bf16 stores, permuted-within-segment layout (8B per (i,reg))
#pragma unroll
        for (int i = 0; i < 4; ++i) {
            const int lr_base = w_row * 64 + i * 16 + quad * 4;
#pragma unroll
            for (int reg = 0; reg < 4; ++reg) {
                const int lr = lr_base + reg;
                const int rid = rows[lr];
                if (rid >= 0) {
                    unsigned short v[4];
#pragma unroll
                    for (int j = 0; j < 4; ++j) v[j] = f2b(acc[i][j][reg]);
                    *(uint2*)(Y + (size_t)rid * H_DIM + d0 + w_col * 64 + m_lane * 4) = *(uint2*)v;
                }
            }
        }
    }
}

// ---------------- K4: combine via LDS de-permute; coalesced loads AND stores ----------------
// block = 2 tokens (4 consecutive Y rows, 8KB). Stage linear into LDS, gather the
// inverse permutation with ds_read_u16, store two float4 per thread.
__global__ __launch_bounds__(256) void k_combine(
    const unsigned short* __restrict__ Y, const float* __restrict__ w_arr,
    float* __restrict__ out)
{
    __shared__ __align__(16) unsigned short Ys[4 * H_DIM];   // rows 4b..4b+3
    const int t = threadIdx.x;
    const int b = blockIdx.x;                 // 4096 blocks, 2 tokens each
    const int wv = t >> 6, lane = t & 63;
    const unsigned short* src = Y + (size_t)b * 4 * H_DIM;
#pragma unroll
    for (int r = 0; r < 2; ++r) {
        __builtin_amdgcn_global_load_lds(
            (GV*)(src + (size_t)r * 2048 + wv * 512 + lane * 8),
            (LV*)(&Ys[r * 2048 + wv * 512]), 16, 0, 0);
    }
    __syncthreads();   // full drain is fine here (single stage)

    const int tok = t >> 7;                   // 0/1 within block
    const int n = 2 * b + tok;
    const int d0 = (t & 127) * 8;             // 8 consecutive output cols
    const int seg = d0 >> 7;
    const int dseg = d0 & 127;
    const int wc = dseg >> 6;
    const int j  = (dseg >> 4) & 3;           // constant across the 8 cols
    const int m0 = dseg & 15;                 // 0 or 8
    // stored idx within row: seg*128 + wc*64 + m*4 + j  (m = m0..m0+7)
    const int sbase = tok * 2 * H_DIM + seg * 128 + wc * 64 + j;
    const float w0 = w_arr[2 * n], w1 = w_arr[2 * n + 1];

    float o[8];
#pragma unroll
    for (int k = 0; k < 8; ++k) {
        int s = sbase + (m0 + k) * 4;
        o[k] = w0 * b2f(Ys[s]) + w1 * b2f(Ys[s + H_DIM]);
    }
    float4* op = (float4*)(out + (size_t)n * H_DIM + d0);
    op[0] = make_float4(o[0], o[1], o[2], o[3]);
    op[1] = make_float4(o[4], o[5], o[6], o[7]);
}

extern "C" void kernel_launch(void* const* d_in, const int* in_sizes, int n_in,
                              void* d_out, int out_size, void* d_ws, size_t ws_size,
                              hipStream_t stream)
{
    const float* tokens   = (const float*)d_in[0]; // fp32 [8192,1024]
    const float* router_w = (const float*)d_in[1]; // fp32 [8,1024]
    const float* router_b = (const float*)d_in[2]; // fp32 [8]
    const float* W        = (const float*)d_in[3]; // fp32 [8,1024,1024]
    float* out = (float*)d_out;                    // fp32 [8192,1024]

    char* ws = (char*)d_ws;
    int*   cnt    = (int*)(ws);                        // 32 B
    int*   sel    = (int*)(ws + 1024);                 // 32 KB
    float* w_arr  = (float*)(ws + 34816);              // 64 KB
    int*   bucket = (int*)(ws + 100352);               // 256 KB
    unsigned short* tokb = (unsigned short*)(ws + 362496);    // 16 MB bf16 tokens  [ends 17139712]
    unsigned short* Bp   = (unsigned short*)(ws + 17139712);  // 16 MB packed bf16 W [ends 33916928]
    unsigned short* Y    = (unsigned short*)(ws + 33916928);  // 32 MB bf16 per-slot outputs (AFTER Bp!)

    k_front  <<<2048 + 1024, 256, 0, stream>>>(tokens, router_w, router_b, W,
                                               sel, w_arr, tokb, Bp);
    k_scan   <<<N_EXP, 256, 0, stream>>>(sel, cnt, bucket);
    k_gemm   <<<GEMM_GRID, 256, 0, stream>>>(tokb, Bp, cnt, bucket, Y);
    k_combine<<<N_TOK * (H_DIM / 8) / 256, 256, 0, stream>>>(Y, w_arr, out);
}

// Round 8
// 188.418 us; speedup vs baseline: 1.1357x; 1.0533x over previous
//
#include <hip/hip_runtime.h>
#include <stdint.h>

// Problem constants (B=4, S=2048, H=1024, E=8, TOP_K=2). All I/O fp32.
#define N_TOK 8192
#define H_DIM 1024
#define N_EXP 8
#define GEMM_GRID 1024   // 4 blocks/CU x 256 CU

typedef __bf16 bf16x8 __attribute__((ext_vector_type(8)));
typedef float floatx4 __attribute__((ext_vector_type(4)));

typedef __attribute__((address_space(1))) void GV;
typedef __attribute__((address_space(3))) void LV;

static __device__ __forceinline__ unsigned short f2b(float f) {
    union { float f; unsigned int i; } v; v.f = f;
    unsigned int u = v.i;
    return (unsigned short)((u + 0x7FFFu + ((u >> 16) & 1u)) >> 16);
}
static __device__ __forceinline__ float b2f(unsigned short u) {
    union { unsigned int i; float f; } v; v.i = ((unsigned int)u) << 16; return v.f;
}

// ---------------- K1: fused router (blocks 0..2047) + W repack (blocks 2048..3071) ----------------
__global__ __launch_bounds__(256) void k_front(
    const float* __restrict__ tokens,
    const float* __restrict__ router_w,
    const float* __restrict__ router_b,
    const float* __restrict__ W,
    int* __restrict__ sel, float* __restrict__ w_arr,
    unsigned short* __restrict__ tokb,
    unsigned short* __restrict__ Bp)
{
    const int t = threadIdx.x;

    if (blockIdx.x >= 2048) {
        const int idx = blockIdx.x - 2048;   // 0..1023
        const int kg = idx & 127;
        const int e  = idx >> 7;
        const int d  = t * 4;
        const float* src = W + ((size_t)e * H_DIM + kg * 8) * H_DIM + d;
        float col[8][4];
#pragma unroll
        for (int j = 0; j < 8; ++j) {
            float4 v = *(const float4*)(src + (size_t)j * H_DIM);
            col[j][0] = v.x; col[j][1] = v.y; col[j][2] = v.z; col[j][3] = v.w;
        }
        unsigned short* dst = Bp + ((size_t)(e * 128 + kg) * H_DIM + d) * 8;
#pragma unroll
        for (int k = 0; k < 4; ++k) {
            unsigned short v[8];
#pragma unroll
            for (int j = 0; j < 8; ++j) v[j] = f2b(col[j][k]);
            *(uint4*)(dst + (size_t)k * 8) = *(uint4*)v;
        }
        return;
    }

    const int wave = t >> 6;
    const int lane = t & 63;
    const int n = blockIdx.x * 4 + wave;

    const float* xp = tokens + (size_t)n * H_DIM + lane * 16;
    float x[16];
#pragma unroll
    for (int i = 0; i < 4; ++i) {
        float4 v = *(const float4*)(xp + i * 4);
        x[i * 4 + 0] = v.x; x[i * 4 + 1] = v.y; x[i * 4 + 2] = v.z; x[i * 4 + 3] = v.w;
    }

    {
        unsigned short xb[16];
#pragma unroll
        for (int j = 0; j < 16; ++j) xb[j] = f2b(x[j]);
        unsigned short* dp = tokb + (size_t)n * H_DIM + lane * 16;
        *(uint4*)(dp)     = *(uint4*)(xb);
        *(uint4*)(dp + 8) = *(uint4*)(xb + 8);
    }

    float acc[N_EXP];
#pragma unroll
    for (int e = 0; e < N_EXP; ++e) {
        const float* wp = router_w + e * H_DIM + lane * 16;
        float s = 0.f;
#pragma unroll
        for (int i = 0; i < 4; ++i) {
            float4 v = *(const float4*)(wp + i * 4);
            s += x[i * 4 + 0] * v.x + x[i * 4 + 1] * v.y
               + x[i * 4 + 2] * v.z + x[i * 4 + 3] * v.w;
        }
        acc[e] = s;
    }

#pragma unroll
    for (int e = 0; e < N_EXP; ++e) {
        float a = acc[e];
#pragma unroll
        for (int off = 32; off > 0; off >>= 1) a += __shfl_xor(a, off);
        acc[e] = a;
    }

    if (lane == 0) {
        float lg[N_EXP];
#pragma unroll
        for (int e = 0; e < N_EXP; ++e) lg[e] = acc[e] + router_b[e];
        int e0 = 0;
#pragma unroll
        for (int e = 1; e < N_EXP; ++e) if (lg[e] > lg[e0]) e0 = e;
        int e1 = -1;
#pragma unroll
        for (int e = 0; e < N_EXP; ++e) {
            if (e == e0) continue;
            if (e1 < 0 || lg[e] > lg[e1]) e1 = e;
        }
        float w0 = 1.f / (1.f + __expf(lg[e1] - lg[e0]));
        float w1 = 1.f - w0;
        sel[n] = e0 | (e1 << 4);
        w_arr[n * 2] = w0;
        w_arr[n * 2 + 1] = w1;
    }
}

// ---------------- K1b: counting sort, one block per expert (deterministic) ----------------
__global__ __launch_bounds__(256) void k_scan(
    const int* __restrict__ sel, int* __restrict__ cnt, int* __restrict__ bucket)
{
    __shared__ int ssel[N_TOK + N_TOK / 32];
    __shared__ int sc[256];
    const int e = blockIdx.x;
    const int t = threadIdx.x;
#pragma unroll
    for (int i = 0; i < 32; ++i) {
        int n = i * 256 + t;
        ssel[n + (n >> 5)] = sel[n];
    }
    __syncthreads();
    const int base = t * 32;
    int c = 0;
#pragma unroll
    for (int i = 0; i < 32; ++i) {
        int n = base + i;
        int s = ssel[n + (n >> 5)];
        c += ((s & 15) == e) + (((s >> 4) & 15) == e);
    }
    sc[t] = c;
    __syncthreads();
    for (int off = 1; off < 256; off <<= 1) {
        int v = (t >= off) ? sc[t - off] : 0;
        __syncthreads();
        sc[t] += v;
        __syncthreads();
    }
    int pos = sc[t] - c;
    if (t == 255) cnt[e] = sc[255];
#pragma unroll
    for (int i = 0; i < 32; ++i) {
        int n = base + i;
        int s = ssel[n + (n >> 5)];
        if ((s & 15) == e)        bucket[e * N_TOK + pos++] = 2 * n;
        if (((s >> 4) & 15) == e) bucket[e * N_TOK + pos++] = 2 * n + 1;
    }
}

// ---------------- K3: grouped GEMM, XCD-chunked, BK=32 dbuf with ASM-ds_read pipeline ----------------
// Staging geometry identical to rounds 5/6 (correctness-proven). The pipeline change (rule #18):
// LDS reads are inline-asm ds_read_b128 so the compiler cannot inject s_waitcnt vmcnt(0) before
// them (LDS-DMA alias ordering defeated rounds 5/6 -- bit-identical schedules). Discipline per kt:
//   issue 4 prefetch gload_lds(buf^1) ; s_waitcnt vmcnt(4)   <- buf's 4 loads landed, prefetch in flight
//   s_barrier (A)                                            <- DMA of buf complete on all waves
//   8x asm ds_read_b128 ; s_waitcnt lgkmcnt(0) ; sched_barrier(0)   <- rule #18 fence
//   s_barrier (B)                                            <- all reads done BEFORE next overwrite
//   setprio(1) ; 32 MFMA ; setprio(0)                        <- register-only, overlaps next phase
// A LDS [2][128rows][32], slot s holds part s^(r&3)^((r>>2)&3); B chunk (kg,d) at (kg*128+d)*8.
// Y row layout (per 128-col segment nt): stored idx s = wc*64 + m_lane*4 + j  <-> col wc*64+j*16+m_lane.
__global__ __launch_bounds__(256, 4) void k_gemm(
    const unsigned short* __restrict__ tokb,
    const unsigned short* __restrict__ Bp,
    const int* __restrict__ cnt, const int* __restrict__ bucket,
    unsigned short* __restrict__ Y)
{
    __shared__ __align__(16) unsigned short Asm[2][128 * 32];    // 2 x 8 KB
    __shared__ __align__(16) unsigned short Bsm[2][4 * 128 * 8]; // 2 x 8 KB
    __shared__ int rows[128];

    const int t = threadIdx.x;
    const int wv = t >> 6, lane = t & 63;
    const int w_row = wv >> 1, w_col = wv & 1;
    const int m_lane = lane & 15, quad = lane >> 4;
    const int aslot = quad ^ (m_lane & 3) ^ ((m_lane >> 2) & 3);
    const int p_sw = (t & 3) ^ ((t >> 2) & 3) ^ ((t >> 4) & 3);

    // LDS byte-offset bases (truncation of the generic address yields the LDS offset on gfx9+)
    const unsigned abase0 = (unsigned)(unsigned long long)&Asm[0][0];
    const unsigned abase1 = (unsigned)(unsigned long long)&Asm[1][0];
    const unsigned bbase0 = (unsigned)(unsigned long long)&Bsm[0][0];
    const unsigned bbase1 = (unsigned)(unsigned long long)&Bsm[1][0];

    int cs[N_EXP];
#pragma unroll
    for (int ee = 0; ee < N_EXP; ++ee) cs[ee] = cnt[ee];
    int T = 0;
#pragma unroll
    for (int ee = 0; ee < N_EXP; ++ee) T += (cs[ee] + 127) >> 7;

    const int x = blockIdx.x & 7;        // physical XCD (round-robin; confirmed round 3)
    const int sblk = blockIdx.x >> 3;
    const int q = T >> 3, r = T & 7;
    const int tstart = (x < r) ? x * (q + 1) : r * (q + 1) + (x - r) * q;
    const int tcnt   = (x < r) ? (q + 1) : q;
    const int nloc   = tcnt * 8;

    for (int l = sblk; l < nloc; l += 128) {
        const int tile = tstart + (l >> 3);
        const int nt   = l & 7;
        int base = 0, e = 0, mt = 0;
#pragma unroll
        for (int ee = 0; ee < N_EXP; ++ee) {
            int te = (cs[ee] + 127) >> 7;
            if (tile >= base && tile < base + te) { e = ee; mt = tile - base; }
            base += te;
        }
        const int cnt_local = cs[e] - mt * 128;
        const int d0 = nt * 128;

        __syncthreads();   // previous item fully done with rows/LDS (full drain once per item)
        if (t < 128)
            rows[t] = (t < cnt_local) ? bucket[e * N_TOK + mt * 128 + t] : -1;
        __syncthreads();

        // staging sources (geometry proven in rounds 5/6)
        const int r0 = t >> 2;
        const int rid0 = rows[r0], rid1 = rows[64 + r0];
        const unsigned short* aptr0 = tokb + (size_t)((rid0 >= 0) ? (rid0 >> 1) : 0) * H_DIM + p_sw * 8;
        const unsigned short* aptr1 = tokb + (size_t)((rid1 >= 0) ? (rid1 >> 1) : 0) * H_DIM + p_sw * 8;
        const int kgt = t >> 7;
        const unsigned short* bb0 = Bp + ((size_t)(e * 128 + kgt)     * H_DIM + d0 + (t & 127)) * 8;
        const unsigned short* bb1 = Bp + ((size_t)(e * 128 + 2 + kgt) * H_DIM + d0 + (t & 127)) * 8;

        floatx4 acc[4][4];
#pragma unroll
        for (int i = 0; i < 4; ++i)
#pragma unroll
            for (int j = 0; j < 4; ++j) acc[i][j] = (floatx4){0.f, 0.f, 0.f, 0.f};

        // prologue: stage kt=0 into buffer 0
        __builtin_amdgcn_global_load_lds((GV*)aptr0, (LV*)(&Asm[0][wv * 512]), 16, 0, 0);
        __builtin_amdgcn_global_load_lds((GV*)aptr1, (LV*)(&Asm[0][2048 + wv * 512]), 16, 0, 0);
        __builtin_amdgcn_global_load_lds((GV*)bb0,   (LV*)(&Bsm[0][wv * 512]), 16, 0, 0);
        __builtin_amdgcn_global_load_lds((GV*)bb1,   (LV*)(&Bsm[0][2048 + wv * 512]), 16, 0, 0);

        for (int kt = 0; kt < H_DIM / 32; ++kt) {
            const int cb = kt & 1;
            if (kt < H_DIM / 32 - 1) {
                const int kn = kt + 1;
                __builtin_amdgcn_global_load_lds(
                    (GV*)(aptr0 + kn * 32), (LV*)(&Asm[cb ^ 1][wv * 512]), 16, 0, 0);
                __builtin_amdgcn_global_load_lds(
                    (GV*)(aptr1 + kn * 32), (LV*)(&Asm[cb ^ 1][2048 + wv * 512]), 16, 0, 0);
                __builtin_amdgcn_global_load_lds(
                    (GV*)(bb0 + (size_t)kn * 32768), (LV*)(&Bsm[cb ^ 1][wv * 512]), 16, 0, 0);
                __builtin_amdgcn_global_load_lds(
                    (GV*)(bb1 + (size_t)kn * 32768), (LV*)(&Bsm[cb ^ 1][2048 + wv * 512]), 16, 0, 0);
                asm volatile("s_waitcnt vmcnt(4)" ::: "memory");
            } else {
                asm volatile("s_waitcnt vmcnt(0)" ::: "memory");
            }
            __builtin_amdgcn_s_barrier();           // (A) buf[cb] DMA complete on all waves

            const unsigned ab = cb ? abase1 : abase0;
            const unsigned bb = cb ? bbase1 : bbase0;
            bf16x8 a[4], b[4];
#pragma unroll
            for (int i = 0; i < 4; ++i) {
                unsigned off = ab + (unsigned)((w_row * 64 + i * 16 + m_lane) * 64 + aslot * 16);
                asm volatile("ds_read_b128 %0, %1" : "=v"(a[i]) : "v"(off));
            }
#pragma unroll
            for (int j = 0; j < 4; ++j) {
                unsigned off = bb + (unsigned)((quad * 128 + w_col * 64 + j * 16 + m_lane) * 16);
                asm volatile("ds_read_b128 %0, %1" : "=v"(b[j]) : "v"(off));
            }
            asm volatile("s_waitcnt lgkmcnt(0)" ::: "memory");
            __builtin_amdgcn_sched_barrier(0);      // rule #18: pin MFMA after the wait
            __builtin_amdgcn_s_barrier();           // (B) all reads of buf[cb] done pre-overwrite

            __builtin_amdgcn_s_setprio(1);
#pragma unroll
            for (int i = 0; i < 4; ++i)
#pragma unroll
                for (int j = 0; j < 4; ++j)
                    acc[i][j] = __builtin_amdgcn_mfma_f32_16x16x32_bf16(a[i], b[j], acc[i][j], 0, 0, 0);
            __builtin_amdgcn_s_setprio(0);
        }

        // epilogue: plain bf16 stores, permuted-within-segment layout
#pragma unroll
        for (int i = 0; i < 4; ++i) {
            const int lr_base = w_row * 64 + i * 16 + quad * 4;
#pragma unroll
            for (int reg = 0; reg < 4; ++reg) {
                const int lr = lr_base + reg;
                const int rid = rows[lr];
                if (rid >= 0) {
                    unsigned short v[4];
#pragma unroll
                    for (int j = 0; j < 4; ++j) v[j] = f2b(acc[i][j][reg]);
                    *(uint2*)(Y + (size_t)rid * H_DIM + d0 + w_col * 64 + m_lane * 4) = *(uint2*)v;
                }
            }
        }
    }
}

// ---------------- K4: combine via LDS de-permute; coalesced loads AND stores ----------------
__global__ __launch_bounds__(256) void k_combine(
    const unsigned short* __restrict__ Y, const float* __restrict__ w_arr,
    float* __restrict__ out)
{
    __shared__ __align__(16) unsigned short Ys[4 * H_DIM];
    const int t = threadIdx.x;
    const int b = blockIdx.x;
    const int wv = t >> 6, lane = t & 63;
    const unsigned short* src = Y + (size_t)b * 4 * H_DIM;
#pragma unroll
    for (int r = 0; r < 2; ++r) {
        __builtin_amdgcn_global_load_lds(
            (GV*)(src + (size_t)r * 2048 + wv * 512 + lane * 8),
            (LV*)(&Ys[r * 2048 + wv * 512]), 16, 0, 0);
    }
    __syncthreads();

    const int tok = t >> 7;
    const int n = 2 * b + tok;
    const int d0 = (t & 127) * 8;
    const int seg = d0 >> 7;
    const int dseg = d0 & 127;
    const int wc = dseg >> 6;
    const int j  = (dseg >> 4) & 3;
    const int m0 = dseg & 15;
    const int sbase = tok * 2 * H_DIM + seg * 128 + wc * 64 + j;
    const float w0 = w_arr[2 * n], w1 = w_arr[2 * n + 1];

    float o[8];
#pragma unroll
    for (int k = 0; k < 8; ++k) {
        int s = sbase + (m0 + k) * 4;
        o[k] = w0 * b2f(Ys[s]) + w1 * b2f(Ys[s + H_DIM]);
    }
    float4* op = (float4*)(out + (size_t)n * H_DIM + d0);
    op[0] = make_float4(o[0], o[1], o[2], o[3]);
    op[1] = make_float4(o[4], o[5], o[6], o[7]);
}

extern "C" void kernel_launch(void* const* d_in, const int* in_sizes, int n_in,
                              void* d_out, int out_size, void* d_ws, size_t ws_size,
                              hipStream_t stream)
{
    const float* tokens   = (const float*)d_in[0]; // fp32 [8192,1024]
    const float* router_w = (const float*)d_in[1]; // fp32 [8,1024]
    const float* router_b = (const float*)d_in[2]; // fp32 [8]
    const float* W        = (const float*)d_in[3]; // fp32 [8,1024,1024]
    float* out = (float*)d_out;                    // fp32 [8192,1024]

    char* ws = (char*)d_ws;
    int*   cnt    = (int*)(ws);                        // 32 B
    int*   sel    = (int*)(ws + 1024);                 // 32 KB
    float* w_arr  = (float*)(ws + 34816);              // 64 KB
    int*   bucket = (int*)(ws + 100352);               // 256 KB
    unsigned short* tokb = (unsigned short*)(ws + 362496);    // 16 MB bf16 tokens
    unsigned short* Bp   = (unsigned short*)(ws + 17139712);  // 16 MB packed bf16 W
    unsigned short* Y    = (unsigned short*)(ws + 33916928);  // 32 MB bf16 per-slot outputs

    k_front  <<<2048 + 1024, 256, 0, stream>>>(tokens, router_w, router_b, W,
                                               sel, w_arr, tokb, Bp);
    k_scan   <<<N_EXP, 256, 0, stream>>>(sel, cnt, bucket);
    k_gemm   <<<GEMM_GRID, 256, 0, stream>>>(tokb, Bp, cnt, bucket, Y);
    k_combine<<<N_TOK * (H_DIM / 8) / 256, 256, 0, stream>>>(Y, w_arr, out);
}

// Round 9
// 178.644 us; speedup vs baseline: 1.1978x; 1.0547x over previous
//
#include <hip/hip_runtime.h>
#include <stdint.h>

// Problem constants (B=4, S=2048, H=1024, E=8, TOP_K=2). All I/O fp32.
#define N_TOK 8192
#define H_DIM 1024
#define N_EXP 8
#define GEMM_GRID 1024   // 4 blocks/CU x 256 CU

typedef __bf16 bf16x8 __attribute__((ext_vector_type(8)));
typedef float floatx4 __attribute__((ext_vector_type(4)));

typedef __attribute__((address_space(1))) void GV;
typedef __attribute__((address_space(3))) void LV;

static __device__ __forceinline__ unsigned short f2b(float f) {
    union { float f; unsigned int i; } v; v.f = f;
    unsigned int u = v.i;
    return (unsigned short)((u + 0x7FFFu + ((u >> 16) & 1u)) >> 16);
}
static __device__ __forceinline__ float b2f(unsigned short u) {
    union { unsigned int i; float f; } v; v.i = ((unsigned int)u) << 16; return v.f;
}

// ---------------- K1: fused router+bucket (blocks 0..1023) + W repack (1024..2047) ----------------
// Router: 8 tokens/block (2 per wave, sharing router_w loads). Bucket built directly via
// block-aggregated device atomics on cnt[8] (order within an expert's bucket is FREE:
// each rid's output depends only on (rid, expert), not tile membership -> deterministic output).
// k_scan is deleted; cnt[] zeroed by a 32B hipMemsetAsync before this kernel.
__global__ __launch_bounds__(256) void k_front(
    const float* __restrict__ tokens,
    const float* __restrict__ router_w,
    const float* __restrict__ router_b,
    const float* __restrict__ W,
    float* __restrict__ w_arr,
    unsigned short* __restrict__ tokb,
    unsigned short* __restrict__ Bp,
    int* __restrict__ cnt, int* __restrict__ bucket)
{
    const int t = threadIdx.x;

    if (blockIdx.x >= 1024) {
        // ---- repack W[e][h][d] fp32 -> Bp[e][h>>3][d][h&7] bf16 (no LDS) ----
        const int idx = blockIdx.x - 1024;   // 0..1023
        const int kg = idx & 127;
        const int e  = idx >> 7;
        const int d  = t * 4;
        const float* src = W + ((size_t)e * H_DIM + kg * 8) * H_DIM + d;
        float col[8][4];
#pragma unroll
        for (int j = 0; j < 8; ++j) {
            float4 v = *(const float4*)(src + (size_t)j * H_DIM);
            col[j][0] = v.x; col[j][1] = v.y; col[j][2] = v.z; col[j][3] = v.w;
        }
        unsigned short* dst = Bp + ((size_t)(e * 128 + kg) * H_DIM + d) * 8;
#pragma unroll
        for (int k = 0; k < 4; ++k) {
            unsigned short v[8];
#pragma unroll
            for (int j = 0; j < 8; ++j) v[j] = f2b(col[j][k]);
            *(uint4*)(dst + (size_t)k * 8) = *(uint4*)v;
        }
        return;
    }

    // ---- router: wave handles 2 tokens; block handles 8 ----
    __shared__ int bcnt[N_EXP];
    __shared__ int blist[N_EXP][16];
    if (t < N_EXP) bcnt[t] = 0;
    __syncthreads();

    const int wv = t >> 6, lane = t & 63;
    const int n0 = blockIdx.x * 8 + wv * 2;   // tokens n0, n0+1

    float x0[16], x1[16];
    const float* xp0 = tokens + (size_t)n0 * H_DIM + lane * 16;
    const float* xp1 = xp0 + H_DIM;
#pragma unroll
    for (int i = 0; i < 4; ++i) {
        float4 v = *(const float4*)(xp0 + i * 4);
        x0[i * 4 + 0] = v.x; x0[i * 4 + 1] = v.y; x0[i * 4 + 2] = v.z; x0[i * 4 + 3] = v.w;
        float4 u = *(const float4*)(xp1 + i * 4);
        x1[i * 4 + 0] = u.x; x1[i * 4 + 1] = u.y; x1[i * 4 + 2] = u.z; x1[i * 4 + 3] = u.w;
    }
    {
        unsigned short xb[16];
#pragma unroll
        for (int j = 0; j < 16; ++j) xb[j] = f2b(x0[j]);
        unsigned short* dp = tokb + (size_t)n0 * H_DIM + lane * 16;
        *(uint4*)(dp) = *(uint4*)(xb); *(uint4*)(dp + 8) = *(uint4*)(xb + 8);
#pragma unroll
        for (int j = 0; j < 16; ++j) xb[j] = f2b(x1[j]);
        dp += H_DIM;
        *(uint4*)(dp) = *(uint4*)(xb); *(uint4*)(dp + 8) = *(uint4*)(xb + 8);
    }

    float a0[N_EXP], a1[N_EXP];
#pragma unroll
    for (int e = 0; e < N_EXP; ++e) {
        const float* wp = router_w + e * H_DIM + lane * 16;
        float s0 = 0.f, s1 = 0.f;
#pragma unroll
        for (int i = 0; i < 4; ++i) {
            float4 v = *(const float4*)(wp + i * 4);
            s0 += x0[i * 4 + 0] * v.x + x0[i * 4 + 1] * v.y + x0[i * 4 + 2] * v.z + x0[i * 4 + 3] * v.w;
            s1 += x1[i * 4 + 0] * v.x + x1[i * 4 + 1] * v.y + x1[i * 4 + 2] * v.z + x1[i * 4 + 3] * v.w;
        }
        a0[e] = s0; a1[e] = s1;
    }
#pragma unroll
    for (int e = 0; e < N_EXP; ++e) {
        float p = a0[e], q = a1[e];
#pragma unroll
        for (int off = 32; off > 0; off >>= 1) { p += __shfl_xor(p, off); q += __shfl_xor(q, off); }
        a0[e] = p; a1[e] = q;
    }

    if (lane == 0) {
#pragma unroll
        for (int k = 0; k < 2; ++k) {
            const int n = n0 + k;
            float lg[N_EXP];
#pragma unroll
            for (int e = 0; e < N_EXP; ++e) lg[e] = (k ? a1[e] : a0[e]) + router_b[e];
            int e0 = 0;
#pragma unroll
            for (int e = 1; e < N_EXP; ++e) if (lg[e] > lg[e0]) e0 = e;
            int e1 = -1;
#pragma unroll
            for (int e = 0; e < N_EXP; ++e) {
                if (e == e0) continue;
                if (e1 < 0 || lg[e] > lg[e1]) e1 = e;
            }
            // collapsed weights: w0 = p0/(p0+p1) = sigmoid(l0-l1); eps terms < fp32 ulp
            float w0 = 1.f / (1.f + __expf(lg[e1] - lg[e0]));
            w_arr[n * 2] = w0;
            w_arr[n * 2 + 1] = 1.f - w0;
            int s0 = atomicAdd(&bcnt[e0], 1); blist[e0][s0] = 2 * n;
            int s1 = atomicAdd(&bcnt[e1], 1); blist[e1][s1] = 2 * n + 1;
        }
    }
    __syncthreads();

    if (t < N_EXP) {
        int c = bcnt[t];
        if (c > 0) {
            int base = atomicAdd(&cnt[t], c);   // device-scope (Guideline 12)
            int* dst = bucket + t * N_TOK + base;
            for (int i = 0; i < c; ++i) dst[i] = blist[t][i];
        }
    }
}

// ---------------- K3: grouped GEMM, 128x128 tiles, XCD-chunked (round-3 proven, 45.8us) ----------------
// XCD x = blockIdx.x & 7 (HW round-robin, confirmed: FETCH 115->29MB) owns a contiguous chunk of
// row-tiles; the 8 nt-segments of a tile run concurrently on the SAME XCD -> A panel L2-shared.
// Known bound: T~131 tiles -> 1080 items on 1024 slots -> 2-round makespan (~2x23us). Pipeline
// variants (rounds 5/6/8) all converge to ~46us; parking this at best-known form.
// Y row layout (per 128-col segment nt): stored index s = wc*64 + m_lane*4 + j
// holds actual col wc*64 + j*16 + m_lane.
__global__ __launch_bounds__(256, 4) void k_gemm(
    const unsigned short* __restrict__ tokb,
    const unsigned short* __restrict__ Bp,
    const int* __restrict__ cnt, const int* __restrict__ bucket,
    unsigned short* __restrict__ Y)
{
    // As: flat [row][64], XOR-swizzled: (row, part) lives at row*64 + (part^(row&7))*8
    __shared__ __align__(16) unsigned short Asm[128 * 64];
    __shared__ __align__(16) unsigned short Bsm[8 * 128 * 8];  // chunk (kg,d) at (kg*128+d)*8
    __shared__ int rows[128];

    const int t = threadIdx.x;
    const int wv = t >> 6, lane = t & 63;
    const int w_row = wv >> 1, w_col = wv & 1;
    const int m_lane = lane & 15, quad = lane >> 4;
    const int r7 = m_lane & 7;
    const int p_sw = (lane & 7) ^ ((lane >> 3) & 7);

    int cs[N_EXP];
#pragma unroll
    for (int ee = 0; ee < N_EXP; ++ee) cs[ee] = cnt[ee];
    int T = 0;
#pragma unroll
    for (int ee = 0; ee < N_EXP; ++ee) T += (cs[ee] + 127) >> 7;

    // bijective chunk split of T tiles over 8 XCDs
    const int x = blockIdx.x & 7;
    const int sblk = blockIdx.x >> 3;    // 0..127 within XCD
    const int q = T >> 3, r = T & 7;
    const int tstart = (x < r) ? x * (q + 1) : r * (q + 1) + (x - r) * q;
    const int tcnt   = (x < r) ? (q + 1) : q;
    const int nloc   = tcnt * 8;

    for (int l = sblk; l < nloc; l += 128) {
        const int tile = tstart + (l >> 3);
        const int nt   = l & 7;
        int base = 0, e = 0, mt = 0;
#pragma unroll
        for (int ee = 0; ee < N_EXP; ++ee) {
            int te = (cs[ee] + 127) >> 7;
            if (tile >= base && tile < base + te) { e = ee; mt = tile - base; }
            base += te;
        }
        const int cnt_local = cs[e] - mt * 128;
        const int d0 = nt * 128;

        __syncthreads();   // previous item fully done with rows/LDS
        if (t < 128)
            rows[t] = (t < cnt_local) ? bucket[e * N_TOK + mt * 128 + t] : -1;
        __syncthreads();

        // A staging: instr i, lane l covers LDS chunk c = i*256+wv*64+l
        // -> row rr = c>>3 = i*32+wv*8+(l>>3), swizzled slot l&7 holds global part p=(l&7)^(rr&7)
        const unsigned short* aptr[4];
#pragma unroll
        for (int i = 0; i < 4; ++i) {
            int rr = i * 32 + wv * 8 + (lane >> 3);
            int rid = rows[rr];
            int tok = (rid >= 0) ? (rid >> 1) : 0;
            aptr[i] = tokb + (size_t)tok * H_DIM + p_sw * 8;
        }
        // B staging: chunk c = i*256+t -> kg' = c>>7 = i*2+(t>>7), d = t&127
        const unsigned short* bbase = Bp
            + ((size_t)(e * 128 + (t >> 7)) * H_DIM + d0 + (t & 127)) * 8;

        floatx4 acc[4][4];
#pragma unroll
        for (int i = 0; i < 4; ++i)
#pragma unroll
            for (int j = 0; j < 4; ++j) acc[i][j] = (floatx4){0.f, 0.f, 0.f, 0.f};

        for (int kt = 0; kt < H_DIM / 64; ++kt) {
#pragma unroll
            for (int i = 0; i < 4; ++i) {
                __builtin_amdgcn_global_load_lds(
                    (GV*)(aptr[i] + kt * 64),
                    (LV*)(&Asm[i * 2048 + wv * 512]), 16, 0, 0);
                __builtin_amdgcn_global_load_lds(
                    (GV*)(bbase + (size_t)i * 16384 + (size_t)kt * 65536),
                    (LV*)(&Bsm[i * 2048 + wv * 512]), 16, 0, 0);
            }
            __syncthreads();

#pragma unroll
            for (int s = 0; s < 2; ++s) {
                bf16x8 a[4], b[4];
#pragma unroll
                for (int i = 0; i < 4; ++i) {
                    int row = w_row * 64 + i * 16 + m_lane;
                    a[i] = *(const bf16x8*)&Asm[row * 64 + ((s * 4 + quad) ^ r7) * 8];
                }
#pragma unroll
                for (int j = 0; j < 4; ++j)
                    b[j] = *(const bf16x8*)&Bsm[((s * 4 + quad) * 128 + w_col * 64 + j * 16 + m_lane) * 8];
#pragma unroll
                for (int i = 0; i < 4; ++i)
#pragma unroll
                    for (int j = 0; j < 4; ++j)
                        acc[i][j] = __builtin_amdgcn_mfma_f32_16x16x32_bf16(a[i], b[j], acc[i][j], 0, 0, 0);
            }
            __syncthreads();
        }

        // epilogue: plain bf16 stores, permuted-within-segment layout (8B per (i,reg))
#pragma unroll
        for (int i = 0; i < 4; ++i) {
            const int lr_base = w_row * 64 + i * 16 + quad * 4;
#pragma unroll
            for (int reg = 0; reg < 4; ++reg) {
                const int lr = lr_base + reg;
                const int rid = rows[lr];
                if (rid >= 0) {
                    unsigned short v[4];
#pragma unroll
                    for (int j = 0; j < 4; ++j) v[j] = f2b(acc[i][j][reg]);
                    *(uint2*)(Y + (size_t)rid * H_DIM + d0 + w_col * 64 + m_lane * 4) = *(uint2*)v;
                }
            }
        }
    }
}

// ---------------- K4: combine via LDS de-permute; coalesced loads AND stores ----------------
__global__ __launch_bounds__(256) void k_combine(
    const unsigned short* __restrict__ Y, const float* __restrict__ w_arr,
    float* __restrict__ out)
{
    __shared__ __align__(16) unsigned short Ys[4 * H_DIM];
    const int t = threadIdx.x;
    const int b = blockIdx.x;
    const int wv = t >> 6, lane = t & 63;
    const unsigned short* src = Y + (size_t)b * 4 * H_DIM;
#pragma unroll
    for (int r = 0; r < 2; ++r) {
        __builtin_amdgcn_global_load_lds(
            (GV*)(src + (size_t)r * 2048 + wv * 512 + lane * 8),
            (LV*)(&Ys[r * 2048 + wv * 512]), 16, 0, 0);
    }
    __syncthreads();

    const int tok = t >> 7;
    const int n = 2 * b + tok;
    const int d0 = (t & 127) * 8;
    const int seg = d0 >> 7;
    const int dseg = d0 & 127;
    const int wc = dseg >> 6;
    const int j  = (dseg >> 4) & 3;
    const int m0 = dseg & 15;
    const int sbase = tok * 2 * H_DIM + seg * 128 + wc * 64 + j;
    const float w0 = w_arr[2 * n], w1 = w_arr[2 * n + 1];

    float o[8];
#pragma unroll
    for (int k = 0; k < 8; ++k) {
        int s = sbase + (m0 + k) * 4;
        o[k] = w0 * b2f(Ys[s]) + w1 * b2f(Ys[s + H_DIM]);
    }
    float4* op = (float4*)(out + (size_t)n * H_DIM + d0);
    op[0] = make_float4(o[0], o[1], o[2], o[3]);
    op[1] = make_float4(o[4], o[5], o[6], o[7]);
}

extern "C" void kernel_launch(void* const* d_in, const int* in_sizes, int n_in,
                              void* d_out, int out_size, void* d_ws, size_t ws_size,
                              hipStream_t stream)
{
    const float* tokens   = (const float*)d_in[0]; // fp32 [8192,1024]
    const float* router_w = (const float*)d_in[1]; // fp32 [8,1024]
    const float* router_b = (const float*)d_in[2]; // fp32 [8]
    const float* W        = (const float*)d_in[3]; // fp32 [8,1024,1024]
    float* out = (float*)d_out;                    // fp32 [8192,1024]

    char* ws = (char*)d_ws;
    int*   cnt    = (int*)(ws);                        // 32 B (zeroed each launch below)
    float* w_arr  = (float*)(ws + 34816);              // 64 KB
    int*   bucket = (int*)(ws + 100352);               // 256 KB
    unsigned short* tokb = (unsigned short*)(ws + 362496);    // 16 MB bf16 tokens
    unsigned short* Bp   = (unsigned short*)(ws + 17139712);  // 16 MB packed bf16 W
    unsigned short* Y    = (unsigned short*)(ws + 33916928);  // 32 MB bf16 per-slot outputs

    hipMemsetAsync(cnt, 0, N_EXP * sizeof(int), stream);   // atomics accumulate into cnt
    k_front  <<<2048, 256, 0, stream>>>(tokens, router_w, router_b, W,
                                        w_arr, tokb, Bp, cnt, bucket);
    k_gemm   <<<GEMM_GRID, 256, 0, stream>>>(tokb, Bp, cnt, bucket, Y);
    k_combine<<<N_TOK * (H_DIM / 8) / 256, 256, 0, stream>>>(Y, w_arr, out);
}